// Round 5
// baseline (214.007 us; speedup 1.0000x reference)
//
#include <hip/hip_runtime.h>

// ZBL pair potential + segment-sum into per-atom energies.
// Inputs (setup_inputs order):
//   d_in[0] Z            (4,)     float32
//   d_in[1] r            (E,)     float32   E = 6,400,000
//   d_in[2] per_atom_energy (N,1) float32   N = 100,000
//   d_in[3] atom_types   (N,)     int32
//   d_in[4] edge_index   (2,E)    int32
// Output: (N,1) float32 = segment_sum(edge_eng, edge_index[0]) + per_atom_energy
//
// R4 post-mortem: LDS-histogram killed the global-atomic wall (WRITE 163->26
// MB, 264->88 us) but 100 KB bins => 1 block/CU, 16 waves, Occupancy 41%,
// VALUBusy 46% -- latency-bound. R5: CHUNK=20000 (80 KB bins) => 2 blocks/CU
// (32 waves); av-first conditional load skips r/bv for ~41% of lanes; memset
// and table kernel folded away (partials fully overwritten; Z^0.23 computed
// per block). 2 launches total.

namespace {
constexpr float PZBL     = 0.23f;
constexpr float A0_INV   = 1.0f / 0.4685f;
constexpr float C1 = 0.02817f, C2 = 0.28022f, C3 = 0.50986f, C4 = 0.18175f;
constexpr float D1 = -0.20162f, D2 = -0.4029f, D3 = -0.94229f, D4 = -3.1998f;
constexpr float QQ       = 14.399645f * 0.5f;
constexpr float RMAX     = 6.0f;
constexpr float RMAX_INV = 1.0f / 6.0f;
constexpr int   CHUNK    = 20000;   // 80000 B bins + 32 B tables <= 81920 B => 2 blocks/CU
constexpr int   BLOCK    = 1024;
constexpr int   S_MAX    = 64;      // edge slices; partials = C*S*CHUNK floats
}

__device__ __forceinline__ float zbl_energy(float rk, int ia, int ib,
                                            const int* __restrict__ types,
                                            const float* s_z, const float* s_zp) {
    float rr = rk * RMAX_INV;
    int ti = types[ia];
    int tj = types[ib];
    float zi = s_z[ti], zj = s_z[tj];
    float x = (s_zp[ti] + s_zp[tj]) * rk * A0_INV;
    float psi = C1 * __expf(D1 * x) + C2 * __expf(D2 * x)
              + C3 * __expf(D3 * x) + C4 * __expf(D4 * x);
    float eng = QQ * zi * zj * psi / rk;
    // p=6 polynomial cutoff: 1 - 28 rr^6 + 48 rr^7 - 21 rr^8
    float rr2 = rr * rr;
    float rr3 = rr2 * rr;
    float rr6 = rr3 * rr3;
    float cutoff = 1.0f + rr6 * (-28.0f + rr * (48.0f - 21.0f * rr));
    return cutoff * eng;
}

__global__ __launch_bounds__(BLOCK) void zbl_chunk_kernel(
    const float* __restrict__ Z,
    const float* __restrict__ r,
    const int*   __restrict__ ei0,
    const int*   __restrict__ ei1,
    const int*   __restrict__ types,
    float*       __restrict__ partials,   // [S*C][CHUNK]
    int n_chunks, int quads_per_slice,
    int n_quads, int n_edges) {
    __shared__ float s_z[4];
    __shared__ float s_zp[4];
    __shared__ float bins[CHUNK];         // 80 KB

    const int tid = threadIdx.x;
    if (tid < 4) {
        float z = Z[tid];
        s_z[tid]  = z;
        s_zp[tid] = powf(z, PZBL);
    }
    for (int i = tid; i < CHUNK; i += BLOCK) bins[i] = 0.0f;
    __syncthreads();

    const int c = blockIdx.x % n_chunks;
    const int s = blockIdx.x / n_chunks;
    const int base = c * CHUNK;

    const int q0 = s * quads_per_slice;
    const int q1 = min(n_quads, q0 + quads_per_slice);
    const float4* r4 = (const float4*)r;
    const int4*   a4 = (const int4*)ei0;
    const int4*   b4 = (const int4*)ei1;

    for (int q = q0 + tid; q < q1; q += BLOCK) {
        int4 av = a4[q];
        unsigned d0 = (unsigned)(av.x - base);
        unsigned d1 = (unsigned)(av.y - base);
        unsigned d2 = (unsigned)(av.z - base);
        unsigned d3 = (unsigned)(av.w - base);
        bool m0 = d0 < (unsigned)CHUNK;
        bool m1 = d1 < (unsigned)CHUNK;
        bool m2 = d2 < (unsigned)CHUNK;
        bool m3 = d3 < (unsigned)CHUNK;
        if (!(m0 | m1 | m2 | m3)) continue;   // ~41% of lanes skip r/bv loads
        float4 rv = r4[q];
        int4   bv = b4[q];
        if (m0 && rv.x < RMAX)
            atomicAdd(&bins[d0], zbl_energy(rv.x, av.x, bv.x, types, s_z, s_zp));
        if (m1 && rv.y < RMAX)
            atomicAdd(&bins[d1], zbl_energy(rv.y, av.y, bv.y, types, s_z, s_zp));
        if (m2 && rv.z < RMAX)
            atomicAdd(&bins[d2], zbl_energy(rv.z, av.z, bv.z, types, s_z, s_zp));
        if (m3 && rv.w < RMAX)
            atomicAdd(&bins[d3], zbl_energy(rv.w, av.w, bv.w, types, s_z, s_zp));
    }
    // Scalar tail (n_edges % 4) — handled once, by the s==0 slice blocks.
    if (s == 0) {
        for (int e = 4 * n_quads + tid; e < n_edges; e += BLOCK) {
            int ia = ei0[e];
            unsigned d = (unsigned)(ia - base);
            if (d >= (unsigned)CHUNK) continue;
            float rk = r[e];
            if (rk >= RMAX) continue;
            atomicAdd(&bins[d], zbl_energy(rk, ia, ei1[e], types, s_z, s_zp));
        }
    }
    __syncthreads();

    // Non-atomic flush: every block owns a private CHUNK region.
    float* dst = partials + (size_t)blockIdx.x * CHUNK;
    for (int i = tid; i < CHUNK; i += BLOCK) dst[i] = bins[i];
}

// out[a] = pae[a] + sum over slices of partials[s*C + c][a - c*CHUNK].
__global__ void zbl_reduce_out(const float* __restrict__ pae,
                               const float* __restrict__ partials,
                               float* __restrict__ out,
                               int n_atoms, int n_chunks, int n_slices) {
    int a = blockIdx.x * blockDim.x + threadIdx.x;
    if (a >= n_atoms) return;
    int c = a / CHUNK;
    int i = a - c * CHUNK;
    const float* p = partials + (size_t)c * CHUNK + i;
    const size_t stride = (size_t)n_chunks * CHUNK;
    float s0 = 0.0f, s1 = 0.0f, s2 = 0.0f, s3 = 0.0f;
    int s = 0;
    for (; s + 4 <= n_slices; s += 4) {
        s0 += p[(size_t)(s + 0) * stride];
        s1 += p[(size_t)(s + 1) * stride];
        s2 += p[(size_t)(s + 2) * stride];
        s3 += p[(size_t)(s + 3) * stride];
    }
    for (; s < n_slices; ++s) s0 += p[(size_t)s * stride];
    out[a] = pae[a] + ((s0 + s1) + (s2 + s3));
}

// ---------- fallback path (ws too small): device-scope atomics into out ----
__global__ void zbl_init_out(const float* __restrict__ pae,
                             float* __restrict__ out, int n) {
    int i = blockIdx.x * blockDim.x + threadIdx.x;
    if (i < n) out[i] = pae[i];
}

__global__ __launch_bounds__(256) void zbl_edge_fallback(
    const float* __restrict__ Z,
    const float* __restrict__ r,
    const int*   __restrict__ ei0,
    const int*   __restrict__ ei1,
    const int*   __restrict__ types,
    float*       __restrict__ out,
    int n_edges) {
    __shared__ float s_z[4];
    __shared__ float s_zp[4];
    if (threadIdx.x < 4) {
        float z = Z[threadIdx.x];
        s_z[threadIdx.x]  = z;
        s_zp[threadIdx.x] = powf(z, PZBL);
    }
    __syncthreads();
    int e = blockIdx.x * blockDim.x + threadIdx.x;
    if (e >= n_edges) return;
    float rk = r[e];
    if (rk >= RMAX) return;
    unsafeAtomicAdd(&out[ei0[e]],
                    zbl_energy(rk, ei0[e], ei1[e], types, s_z, s_zp));
}

extern "C" void kernel_launch(void* const* d_in, const int* in_sizes, int n_in,
                              void* d_out, int out_size, void* d_ws, size_t ws_size,
                              hipStream_t stream) {
    const float* Z     = (const float*)d_in[0];
    const float* r     = (const float*)d_in[1];
    const float* pae   = (const float*)d_in[2];
    const int*   types = (const int*)d_in[3];
    const int*   ei    = (const int*)d_in[4];

    const int n_edges = in_sizes[1];
    const int n_atoms = in_sizes[2];

    float* out = (float*)d_out;
    float* partials = (float*)d_ws;

    const int n_chunks = (n_atoms + CHUNK - 1) / CHUNK;   // 5 for N=100K

    // Pick slice count that fits the workspace.
    int S = S_MAX;
    while (S > 1 && (size_t)n_chunks * S * CHUNK * sizeof(float) > ws_size) {
        S >>= 1;
    }
    const bool use_lds_path =
        (size_t)n_chunks * S * CHUNK * sizeof(float) <= ws_size;

    if (use_lds_path) {
        // int4 casts on ei1 = ei + n_edges need 16B alignment; if n_edges is
        // not a multiple of 4, process everything through the scalar tail.
        const int n_quads = (n_edges & 3) ? 0 : (n_edges >> 2);
        const int quads_per_slice = (n_quads + S - 1) / S;
        zbl_chunk_kernel<<<n_chunks * S, BLOCK, 0, stream>>>(
            Z, r, ei, ei + n_edges, types, partials,
            n_chunks, quads_per_slice, n_quads, n_edges);
        zbl_reduce_out<<<(n_atoms + 255) / 256, 256, 0, stream>>>(
            pae, partials, out, n_atoms, n_chunks, S);
    } else {
        zbl_init_out<<<(n_atoms + 255) / 256, 256, 0, stream>>>(pae, out, n_atoms);
        zbl_edge_fallback<<<(n_edges + 255) / 256, 256, 0, stream>>>(
            Z, r, ei, ei + n_edges, types, out, n_edges);
    }
}

// Round 6
// 194.398 us; speedup vs baseline: 1.1009x; 1.1009x over previous
//
#include <hip/hip_runtime.h>

// ZBL pair potential + segment-sum into per-atom energies.
// Inputs (setup_inputs order):
//   d_in[0] Z            (4,)     float32
//   d_in[1] r            (E,)     float32   E = 6,400,000
//   d_in[2] per_atom_energy (N,1) float32   N = 100,000
//   d_in[3] atom_types   (N,)     int32
//   d_in[4] edge_index   (2,E)    int32
// Output: (N,1) float32 = segment_sum(edge_eng, edge_index[0]) + per_atom_energy
//
// R5 post-mortem: CHUNK=20000 did NOT give 2 blocks/CU (occupancy 42.9% vs
// 42.8%) and the 5th scan added 25% work -> regression. Revert to CHUNK=25600.
// R4's limiter: per-edge chain (membership -> loads -> 2 L2 gathers -> 4 exp
// -> ds_add) at only 16 waves/CU. R6: two-phase. Phase 1 (high occupancy,
// tiny LDS) computes masked edge energy once, writes packed (dest,eng) 8B
// records. Phase 2 (R4 grid, 100KB bins) does only load->test->ds_add;
// records are L3-resident so the 4x rescan is cheap.

namespace {
constexpr float PZBL     = 0.23f;
constexpr float A0_INV   = 1.0f / 0.4685f;
constexpr float C1 = 0.02817f, C2 = 0.28022f, C3 = 0.50986f, C4 = 0.18175f;
constexpr float D1 = -0.20162f, D2 = -0.4029f, D3 = -0.94229f, D4 = -3.1998f;
constexpr float QQ       = 14.399645f * 0.5f;
constexpr float RMAX     = 6.0f;
constexpr float RMAX_INV = 1.0f / 6.0f;
constexpr int   CHUNK    = 25600;   // 100 KB fp32 bins (R4-proven best)
constexpr int   BLOCK    = 1024;    // phase-2 block
constexpr int   P1_BLOCK = 256;     // phase-1 block (high occupancy)
constexpr int   S_MAX    = 64;      // edge slices
}

// Masked ZBL edge energy (0 beyond cutoff). Gathers ti/tj from global types.
__device__ __forceinline__ float edge_eng(float rk, int ia, int ib,
                                          const int* __restrict__ types,
                                          const float* s_z, const float* s_zp) {
    if (rk >= RMAX) return 0.0f;
    int ti = types[ia];
    int tj = types[ib];
    float zi = s_z[ti], zj = s_z[tj];
    float x = (s_zp[ti] + s_zp[tj]) * rk * A0_INV;
    float psi = C1 * __expf(D1 * x) + C2 * __expf(D2 * x)
              + C3 * __expf(D3 * x) + C4 * __expf(D4 * x);
    float eng = QQ * zi * zj * psi / rk;
    float rr = rk * RMAX_INV;
    // p=6 polynomial cutoff: 1 - 28 rr^6 + 48 rr^7 - 21 rr^8
    float rr2 = rr * rr;
    float rr3 = rr2 * rr;
    float rr6 = rr3 * rr3;
    float cutoff = 1.0f + rr6 * (-28.0f + rr * (48.0f - 21.0f * rr));
    return cutoff * eng;
}

// Phase 1: stream edges, write packed records (dest:int, energy:float-bits).
__global__ __launch_bounds__(P1_BLOCK) void zbl_energy_kernel(
    const float* __restrict__ Z,
    const float* __restrict__ r,
    const int*   __restrict__ ei0,
    const int*   __restrict__ ei1,
    const int*   __restrict__ types,
    int4*        __restrict__ rec4,   // 2 int4 per quad of edges
    int2*        __restrict__ rec2,   // scalar view (tail)
    int n_quads, int n_edges) {
    __shared__ float s_z[4];
    __shared__ float s_zp[4];
    if (threadIdx.x < 4) {
        float z = Z[threadIdx.x];
        s_z[threadIdx.x]  = z;
        s_zp[threadIdx.x] = powf(z, PZBL);
    }
    __syncthreads();

    int q = blockIdx.x * P1_BLOCK + threadIdx.x;
    if (q < n_quads) {
        float4 rv = ((const float4*)r)[q];
        int4   av = ((const int4*)ei0)[q];
        int4   bv = ((const int4*)ei1)[q];
        float e0 = edge_eng(rv.x, av.x, bv.x, types, s_z, s_zp);
        float e1 = edge_eng(rv.y, av.y, bv.y, types, s_z, s_zp);
        float e2 = edge_eng(rv.z, av.z, bv.z, types, s_z, s_zp);
        float e3 = edge_eng(rv.w, av.w, bv.w, types, s_z, s_zp);
        rec4[2 * q]     = make_int4(av.x, __float_as_int(e0),
                                    av.y, __float_as_int(e1));
        rec4[2 * q + 1] = make_int4(av.z, __float_as_int(e2),
                                    av.w, __float_as_int(e3));
    }
    // Scalar tail (n_edges % 4), handled by block 0.
    if (blockIdx.x == 0) {
        for (int e = 4 * n_quads + threadIdx.x; e < n_edges; e += P1_BLOCK) {
            int ia = ei0[e];
            float eng = edge_eng(r[e], ia, ei1[e], types, s_z, s_zp);
            rec2[e] = make_int2(ia, __float_as_int(eng));
        }
    }
}

// Phase 2: minimal loop — load records, membership test, ds_add, flush.
__global__ __launch_bounds__(BLOCK) void zbl_bin_kernel(
    const int4* __restrict__ rec4,
    const int2* __restrict__ rec2,
    float*      __restrict__ partials,   // [S*C][CHUNK]
    int n_chunks, int rq_per_slice, int n_rq, int n_records) {
    __shared__ float bins[CHUNK];        // 100 KB
    for (int i = threadIdx.x; i < CHUNK; i += BLOCK) bins[i] = 0.0f;
    __syncthreads();

    const int c = blockIdx.x % n_chunks;
    const int s = blockIdx.x / n_chunks;
    const int base = c * CHUNK;

    const int q0 = s * rq_per_slice;
    const int q1 = min(n_rq, q0 + rq_per_slice);
    for (int q = q0 + threadIdx.x; q < q1; q += BLOCK) {
        int4 p0 = rec4[2 * q];
        int4 p1 = rec4[2 * q + 1];
        unsigned d0 = (unsigned)(p0.x - base);
        unsigned d1 = (unsigned)(p0.z - base);
        unsigned d2 = (unsigned)(p1.x - base);
        unsigned d3 = (unsigned)(p1.z - base);
        if (d0 < (unsigned)CHUNK && p0.y != 0)
            atomicAdd(&bins[d0], __int_as_float(p0.y));
        if (d1 < (unsigned)CHUNK && p0.w != 0)
            atomicAdd(&bins[d1], __int_as_float(p0.w));
        if (d2 < (unsigned)CHUNK && p1.y != 0)
            atomicAdd(&bins[d2], __int_as_float(p1.y));
        if (d3 < (unsigned)CHUNK && p1.w != 0)
            atomicAdd(&bins[d3], __int_as_float(p1.w));
    }
    // Scalar record tail, handled once by s==0 blocks.
    if (s == 0) {
        for (int e = 4 * n_rq + threadIdx.x; e < n_records; e += BLOCK) {
            int2 p = rec2[e];
            unsigned d = (unsigned)(p.x - base);
            if (d < (unsigned)CHUNK && p.y != 0)
                atomicAdd(&bins[d], __int_as_float(p.y));
        }
    }
    __syncthreads();

    float* dst = partials + (size_t)blockIdx.x * CHUNK;
    for (int i = threadIdx.x; i < CHUNK; i += BLOCK) dst[i] = bins[i];
}

// out[a] = pae[a] + sum over slices of partials[s*C + c][a - c*CHUNK].
__global__ void zbl_reduce_out(const float* __restrict__ pae,
                               const float* __restrict__ partials,
                               float* __restrict__ out,
                               int n_atoms, int n_chunks, int n_slices) {
    int a = blockIdx.x * blockDim.x + threadIdx.x;
    if (a >= n_atoms) return;
    int c = a / CHUNK;
    int i = a - c * CHUNK;
    const float* p = partials + (size_t)c * CHUNK + i;
    const size_t stride = (size_t)n_chunks * CHUNK;
    float s0 = 0.0f, s1 = 0.0f, s2 = 0.0f, s3 = 0.0f;
    int s = 0;
    for (; s + 4 <= n_slices; s += 4) {
        s0 += p[(size_t)(s + 0) * stride];
        s1 += p[(size_t)(s + 1) * stride];
        s2 += p[(size_t)(s + 2) * stride];
        s3 += p[(size_t)(s + 3) * stride];
    }
    for (; s < n_slices; ++s) s0 += p[(size_t)s * stride];
    out[a] = pae[a] + ((s0 + s1) + (s2 + s3));
}

// ---------- single-phase fallback (R4 structure, ws >= 26 MB) --------------
__global__ __launch_bounds__(BLOCK) void zbl_chunk_kernel(
    const float* __restrict__ Z,
    const float* __restrict__ r,
    const int*   __restrict__ ei0,
    const int*   __restrict__ ei1,
    const int*   __restrict__ types,
    float*       __restrict__ partials,
    int n_chunks, int quads_per_slice,
    int n_quads, int n_edges) {
    __shared__ float s_z[4];
    __shared__ float s_zp[4];
    __shared__ float bins[CHUNK];
    const int tid = threadIdx.x;
    if (tid < 4) {
        float z = Z[tid];
        s_z[tid]  = z;
        s_zp[tid] = powf(z, PZBL);
    }
    for (int i = tid; i < CHUNK; i += BLOCK) bins[i] = 0.0f;
    __syncthreads();
    const int c = blockIdx.x % n_chunks;
    const int s = blockIdx.x / n_chunks;
    const int base = c * CHUNK;
    const int q0 = s * quads_per_slice;
    const int q1 = min(n_quads, q0 + quads_per_slice);
    for (int q = q0 + tid; q < q1; q += BLOCK) {
        int4 av = ((const int4*)ei0)[q];
        unsigned d0 = (unsigned)(av.x - base);
        unsigned d1 = (unsigned)(av.y - base);
        unsigned d2 = (unsigned)(av.z - base);
        unsigned d3 = (unsigned)(av.w - base);
        bool m0 = d0 < (unsigned)CHUNK, m1 = d1 < (unsigned)CHUNK;
        bool m2 = d2 < (unsigned)CHUNK, m3 = d3 < (unsigned)CHUNK;
        if (!(m0 | m1 | m2 | m3)) continue;
        float4 rv = ((const float4*)r)[q];
        int4   bv = ((const int4*)ei1)[q];
        if (m0) { float e = edge_eng(rv.x, av.x, bv.x, types, s_z, s_zp);
                  if (e != 0.0f) atomicAdd(&bins[d0], e); }
        if (m1) { float e = edge_eng(rv.y, av.y, bv.y, types, s_z, s_zp);
                  if (e != 0.0f) atomicAdd(&bins[d1], e); }
        if (m2) { float e = edge_eng(rv.z, av.z, bv.z, types, s_z, s_zp);
                  if (e != 0.0f) atomicAdd(&bins[d2], e); }
        if (m3) { float e = edge_eng(rv.w, av.w, bv.w, types, s_z, s_zp);
                  if (e != 0.0f) atomicAdd(&bins[d3], e); }
    }
    if (s == 0) {
        for (int e = 4 * n_quads + tid; e < n_edges; e += BLOCK) {
            int ia = ei0[e];
            unsigned d = (unsigned)(ia - base);
            if (d >= (unsigned)CHUNK) continue;
            float e2 = edge_eng(r[e], ia, ei1[e], types, s_z, s_zp);
            if (e2 != 0.0f) atomicAdd(&bins[d], e2);
        }
    }
    __syncthreads();
    float* dst = partials + (size_t)blockIdx.x * CHUNK;
    for (int i = tid; i < CHUNK; i += BLOCK) dst[i] = bins[i];
}

// ---------- last-resort fallback: device-scope atomics into out ------------
__global__ void zbl_init_out(const float* __restrict__ pae,
                             float* __restrict__ out, int n) {
    int i = blockIdx.x * blockDim.x + threadIdx.x;
    if (i < n) out[i] = pae[i];
}

__global__ __launch_bounds__(256) void zbl_edge_fallback(
    const float* __restrict__ Z,
    const float* __restrict__ r,
    const int*   __restrict__ ei0,
    const int*   __restrict__ ei1,
    const int*   __restrict__ types,
    float*       __restrict__ out,
    int n_edges) {
    __shared__ float s_z[4];
    __shared__ float s_zp[4];
    if (threadIdx.x < 4) {
        float z = Z[threadIdx.x];
        s_z[threadIdx.x]  = z;
        s_zp[threadIdx.x] = powf(z, PZBL);
    }
    __syncthreads();
    int e = blockIdx.x * blockDim.x + threadIdx.x;
    if (e >= n_edges) return;
    float eng = edge_eng(r[e], ei0[e], ei1[e], types, s_z, s_zp);
    if (eng != 0.0f) unsafeAtomicAdd(&out[ei0[e]], eng);
}

extern "C" void kernel_launch(void* const* d_in, const int* in_sizes, int n_in,
                              void* d_out, int out_size, void* d_ws, size_t ws_size,
                              hipStream_t stream) {
    const float* Z     = (const float*)d_in[0];
    const float* r     = (const float*)d_in[1];
    const float* pae   = (const float*)d_in[2];
    const int*   types = (const int*)d_in[3];
    const int*   ei    = (const int*)d_in[4];

    const int n_edges = in_sizes[1];
    const int n_atoms = in_sizes[2];

    float* out = (float*)d_out;

    const int n_chunks = (n_atoms + CHUNK - 1) / CHUNK;   // 4 for N=100K
    const int n_quads  = (n_edges & 3) ? 0 : (n_edges >> 2);  // alignment guard
    const size_t rec_bytes = (size_t)n_edges * 8;
    const size_t part_floats = (size_t)n_chunks * S_MAX * CHUNK;

    const bool two_phase =
        rec_bytes + part_floats * sizeof(float) <= ws_size;
    const bool one_phase =
        part_floats * sizeof(float) <= ws_size;

    if (two_phase) {
        int2* rec2 = (int2*)d_ws;
        int4* rec4 = (int4*)d_ws;
        float* partials = (float*)((char*)d_ws + rec_bytes);

        const int p1_grid = n_quads ? (n_quads + P1_BLOCK - 1) / P1_BLOCK : 1;
        zbl_energy_kernel<<<p1_grid, P1_BLOCK, 0, stream>>>(
            Z, r, ei, ei + n_edges, types, rec4, rec2, n_quads, n_edges);

        const int n_rq = n_edges >> 2;  // records always 16B-aligned in ws
        const int rq_per_slice = (n_rq + S_MAX - 1) / S_MAX;
        zbl_bin_kernel<<<n_chunks * S_MAX, BLOCK, 0, stream>>>(
            rec4, rec2, partials, n_chunks, rq_per_slice, n_rq, n_edges);

        zbl_reduce_out<<<(n_atoms + 255) / 256, 256, 0, stream>>>(
            pae, partials, out, n_atoms, n_chunks, S_MAX);
    } else if (one_phase) {
        float* partials = (float*)d_ws;
        const int quads_per_slice = (n_quads + S_MAX - 1) / S_MAX;
        zbl_chunk_kernel<<<n_chunks * S_MAX, BLOCK, 0, stream>>>(
            Z, r, ei, ei + n_edges, types, partials,
            n_chunks, quads_per_slice, n_quads, n_edges);
        zbl_reduce_out<<<(n_atoms + 255) / 256, 256, 0, stream>>>(
            pae, partials, out, n_atoms, n_chunks, S_MAX);
    } else {
        zbl_init_out<<<(n_atoms + 255) / 256, 256, 0, stream>>>(pae, out, n_atoms);
        zbl_edge_fallback<<<(n_edges + 255) / 256, 256, 0, stream>>>(
            Z, r, ei, ei + n_edges, types, out, n_edges);
    }
}

// Round 7
// 166.907 us; speedup vs baseline: 1.2822x; 1.1647x over previous
//
#include <hip/hip_runtime.h>

// ZBL pair potential + segment-sum into per-atom energies.
// Inputs (setup_inputs order):
//   d_in[0] Z            (4,)     float32
//   d_in[1] r            (E,)     float32   E = 6,400,000
//   d_in[2] per_atom_energy (N,1) float32   N = 100,000
//   d_in[3] atom_types   (N,)     int32
//   d_in[4] edge_index   (2,E)    int32
// Output: (N,1) float32 = segment_sum(edge_eng, edge_index[0]) + per_atom_energy
//
// R6 post-mortem: phase-1 energy kernel latency-bound (VALUBusy 15%) on the
// 2 random `types` gathers/edge -- 400 KB table = L2-latency splintered
// transactions. R7: pack types to 2 bits/atom (25 KB for 100K atoms), load
// the WHOLE map into LDS next to the 100 KB bins (125 KB < 160 KB/CU), and
// go back to the proven R4 single-pass chunk kernel. Gathers become ~6-cyc
// LDS reads; type-pair constants come from 16-entry LDS tables; av-first
// early-out skips r/bv loads for all-out quads.

namespace {
constexpr float PZBL     = 0.23f;
constexpr float A0_INV   = 1.0f / 0.4685f;
constexpr float C1 = 0.02817f, C2 = 0.28022f, C3 = 0.50986f, C4 = 0.18175f;
constexpr float D1 = -0.20162f, D2 = -0.4029f, D3 = -0.94229f, D4 = -3.1998f;
constexpr float QQ       = 14.399645f * 0.5f;
constexpr float RMAX     = 6.0f;
constexpr float RMAX_INV = 1.0f / 6.0f;
constexpr int   CHUNK    = 25600;   // 100 KB fp32 bins (R4-proven)
constexpr int   BLOCK    = 1024;
constexpr int   S_MAX    = 64;      // edge slices; grid = 4*64 = 256 blocks
constexpr int   TPW_MAX  = 6400;    // packed-type words in LDS (<= 102400 atoms)
}

// Pack atom_types (values 0..3) to 2 bits/atom: word w holds atoms 16w..16w+15.
__global__ void zbl_pack_types(const int* __restrict__ types,
                               unsigned* __restrict__ tpw,
                               int n_words, int n_atoms) {
    int w = blockIdx.x * blockDim.x + threadIdx.x;
    if (w >= n_words) return;
    unsigned v = 0;
    int base = w * 16;
    int m = min(16, n_atoms - base);
    for (int j = 0; j < m; ++j)
        v |= ((unsigned)types[base + j] & 3u) << (2 * j);
    tpw[w] = v;
}

// Single-pass chunk kernel: LDS bins + LDS packed types + LDS pair tables.
__global__ __launch_bounds__(BLOCK) void zbl_chunk_kernel(
    const float*    __restrict__ Z,
    const float*    __restrict__ r,
    const int*      __restrict__ ei0,
    const int*      __restrict__ ei1,
    const unsigned* __restrict__ tpw,
    float*          __restrict__ partials,   // [S*C][CHUNK]
    int n_chunks, int n_tp_words, int quads_per_slice,
    int n_quads, int n_edges) {
    __shared__ float    bins[CHUNK];      // 100 KB
    __shared__ unsigned s_tp[TPW_MAX];    // 25 KB: 2-bit types, ALL atoms
    __shared__ float    s_zz[16];         // QQ * Z[ti] * Z[tj]
    __shared__ float    s_zx[16];         // (Z[ti]^p + Z[tj]^p) / a0

    const int tid = threadIdx.x;
    for (int i = tid; i < n_tp_words; i += BLOCK) s_tp[i] = tpw[i];
    if (tid < 16) {
        int ti = tid >> 2, tj = tid & 3;
        float zi = Z[ti], zj = Z[tj];
        s_zz[tid] = QQ * zi * zj;
        s_zx[tid] = (powf(zi, PZBL) + powf(zj, PZBL)) * A0_INV;
    }
    for (int i = tid; i < CHUNK; i += BLOCK) bins[i] = 0.0f;
    __syncthreads();

    const int c = blockIdx.x % n_chunks;
    const int s = blockIdx.x / n_chunks;
    const int base = c * CHUNK;

    auto edge = [&](float rk, int ia, int ib, unsigned d) {
        if (rk >= RMAX) return;
        unsigned ti = (s_tp[ia >> 4] >> ((ia & 15) * 2)) & 3u;
        unsigned tj = (s_tp[ib >> 4] >> ((ib & 15) * 2)) & 3u;
        int tp = (int)((ti << 2) | tj);
        float x = s_zx[tp] * rk;
        float psi = C1 * __expf(D1 * x) + C2 * __expf(D2 * x)
                  + C3 * __expf(D3 * x) + C4 * __expf(D4 * x);
        float eng = s_zz[tp] * psi * __builtin_amdgcn_rcpf(rk);
        float rr = rk * RMAX_INV;
        // p=6 polynomial cutoff: 1 - 28 rr^6 + 48 rr^7 - 21 rr^8
        float rr2 = rr * rr;
        float rr3 = rr2 * rr;
        float rr6 = rr3 * rr3;
        float cutoff = 1.0f + rr6 * (-28.0f + rr * (48.0f - 21.0f * rr));
        atomicAdd(&bins[d], cutoff * eng);
    };

    const int q0 = s * quads_per_slice;
    const int q1 = min(n_quads, q0 + quads_per_slice);
    const float4* r4 = (const float4*)r;
    const int4*   a4 = (const int4*)ei0;
    const int4*   b4 = (const int4*)ei1;

    for (int q = q0 + tid; q < q1; q += BLOCK) {
        int4 av = a4[q];
        unsigned d0 = (unsigned)(av.x - base);
        unsigned d1 = (unsigned)(av.y - base);
        unsigned d2 = (unsigned)(av.z - base);
        unsigned d3 = (unsigned)(av.w - base);
        bool m0 = d0 < (unsigned)CHUNK, m1 = d1 < (unsigned)CHUNK;
        bool m2 = d2 < (unsigned)CHUNK, m3 = d3 < (unsigned)CHUNK;
        if (!(m0 | m1 | m2 | m3)) continue;   // skip r/bv for all-out quads
        float4 rv = r4[q];
        int4   bv = b4[q];
        if (m0) edge(rv.x, av.x, bv.x, d0);
        if (m1) edge(rv.y, av.y, bv.y, d1);
        if (m2) edge(rv.z, av.z, bv.z, d2);
        if (m3) edge(rv.w, av.w, bv.w, d3);
    }
    // Scalar tail (n_edges % 4), handled once by the s==0 blocks.
    if (s == 0) {
        for (int e = 4 * n_quads + tid; e < n_edges; e += BLOCK) {
            int ia = ei0[e];
            unsigned d = (unsigned)(ia - base);
            if (d < (unsigned)CHUNK) edge(r[e], ia, ei1[e], d);
        }
    }
    __syncthreads();

    // Non-atomic flush: every block owns a private CHUNK region.
    float* dst = partials + (size_t)blockIdx.x * CHUNK;
    for (int i = tid; i < CHUNK; i += BLOCK) dst[i] = bins[i];
}

// out[a] = pae[a] + sum over slices of partials[s*C + c][a - c*CHUNK].
__global__ void zbl_reduce_out(const float* __restrict__ pae,
                               const float* __restrict__ partials,
                               float* __restrict__ out,
                               int n_atoms, int n_chunks, int n_slices) {
    int a = blockIdx.x * blockDim.x + threadIdx.x;
    if (a >= n_atoms) return;
    int c = a / CHUNK;
    int i = a - c * CHUNK;
    const float* p = partials + (size_t)c * CHUNK + i;
    const size_t stride = (size_t)n_chunks * CHUNK;
    float s0 = 0.0f, s1 = 0.0f, s2 = 0.0f, s3 = 0.0f;
    int s = 0;
    for (; s + 4 <= n_slices; s += 4) {
        s0 += p[(size_t)(s + 0) * stride];
        s1 += p[(size_t)(s + 1) * stride];
        s2 += p[(size_t)(s + 2) * stride];
        s3 += p[(size_t)(s + 3) * stride];
    }
    for (; s < n_slices; ++s) s0 += p[(size_t)s * stride];
    out[a] = pae[a] + ((s0 + s1) + (s2 + s3));
}

// ---------- last-resort fallback: device-scope atomics into out ------------
__global__ void zbl_init_out(const float* __restrict__ pae,
                             float* __restrict__ out, int n) {
    int i = blockIdx.x * blockDim.x + threadIdx.x;
    if (i < n) out[i] = pae[i];
}

__global__ __launch_bounds__(256) void zbl_edge_fallback(
    const float* __restrict__ Z,
    const float* __restrict__ r,
    const int*   __restrict__ ei0,
    const int*   __restrict__ ei1,
    const int*   __restrict__ types,
    float*       __restrict__ out,
    int n_edges) {
    __shared__ float s_z[4];
    __shared__ float s_zp[4];
    if (threadIdx.x < 4) {
        float z = Z[threadIdx.x];
        s_z[threadIdx.x]  = z;
        s_zp[threadIdx.x] = powf(z, PZBL);
    }
    __syncthreads();
    int e = blockIdx.x * blockDim.x + threadIdx.x;
    if (e >= n_edges) return;
    float rk = r[e];
    if (rk >= RMAX) return;
    int ia = ei0[e], ib = ei1[e];
    int ti = types[ia], tj = types[ib];
    float x = (s_zp[ti] + s_zp[tj]) * rk * A0_INV;
    float psi = C1 * __expf(D1 * x) + C2 * __expf(D2 * x)
              + C3 * __expf(D3 * x) + C4 * __expf(D4 * x);
    float eng = QQ * s_z[ti] * s_z[tj] * psi / rk;
    float rr = rk * RMAX_INV;
    float rr2 = rr * rr, rr3 = rr2 * rr, rr6 = rr3 * rr3;
    float cutoff = 1.0f + rr6 * (-28.0f + rr * (48.0f - 21.0f * rr));
    unsafeAtomicAdd(&out[ia], cutoff * eng);
}

extern "C" void kernel_launch(void* const* d_in, const int* in_sizes, int n_in,
                              void* d_out, int out_size, void* d_ws, size_t ws_size,
                              hipStream_t stream) {
    const float* Z     = (const float*)d_in[0];
    const float* r     = (const float*)d_in[1];
    const float* pae   = (const float*)d_in[2];
    const int*   types = (const int*)d_in[3];
    const int*   ei    = (const int*)d_in[4];

    const int n_edges = in_sizes[1];
    const int n_atoms = in_sizes[2];

    float* out = (float*)d_out;

    const int n_chunks   = (n_atoms + CHUNK - 1) / CHUNK;   // 4 for N=100K
    const int n_tp_words = (n_atoms + 15) / 16;             // 6250 for N=100K
    const int n_quads    = (n_edges & 3) ? 0 : (n_edges >> 2);

    const size_t tp_bytes    = ((size_t)n_tp_words * 4 + 15) & ~(size_t)15;
    const size_t part_floats = (size_t)n_chunks * S_MAX * CHUNK;

    const bool lds_path =
        n_tp_words <= TPW_MAX &&
        tp_bytes + part_floats * sizeof(float) <= ws_size;

    if (lds_path) {
        unsigned* tpw = (unsigned*)d_ws;
        float* partials = (float*)((char*)d_ws + tp_bytes);

        zbl_pack_types<<<(n_tp_words + 255) / 256, 256, 0, stream>>>(
            types, tpw, n_tp_words, n_atoms);

        const int quads_per_slice = (n_quads + S_MAX - 1) / S_MAX;
        zbl_chunk_kernel<<<n_chunks * S_MAX, BLOCK, 0, stream>>>(
            Z, r, ei, ei + n_edges, tpw, partials,
            n_chunks, n_tp_words, quads_per_slice, n_quads, n_edges);

        zbl_reduce_out<<<(n_atoms + 255) / 256, 256, 0, stream>>>(
            pae, partials, out, n_atoms, n_chunks, S_MAX);
    } else {
        zbl_init_out<<<(n_atoms + 255) / 256, 256, 0, stream>>>(pae, out, n_atoms);
        zbl_edge_fallback<<<(n_edges + 255) / 256, 256, 0, stream>>>(
            Z, r, ei, ei + n_edges, types, out, n_edges);
    }
}